// Round 3
// baseline (17424.402 us; speedup 1.0000x reference)
//
#include <hip/hip_runtime.h>
#include <cstdint>
#include <cstddef>

#define DMODEL 512
#define NHEAD 8
#define HD 64

// jax.random.randint(fold_in(key(42), l), (L,U), 0, LK) with LK = pow2:
//   k1, k2 = split(folded); idx = random_bits(k2) & (LK-1)
// 1 = partitionable (JAX >= 0.4.36 default): k2 = block(folded,(0,1)); bits = out0^out1 of block(k2,(0,i))
// 0 = legacy: k2 = (out1 of block(folded,(0,2)), out1 of block(folded,(1,3))); bits via half-split iota
#define IDX_VARIANT 1

// ---------------------------------------------------------------- threefry
__device__ __forceinline__ uint32_t rotl32(uint32_t x, int r) {
  return (x << r) | (x >> (32 - r));
}

__device__ __forceinline__ void tf_block(uint32_t k0, uint32_t k1,
                                         uint32_t& x0, uint32_t& x1) {
  uint32_t ks0 = k0, ks1 = k1, ks2 = k0 ^ k1 ^ 0x1BD11BDAu;
  x0 += ks0; x1 += ks1;
  x0 += x1; x1 = rotl32(x1, 13); x1 ^= x0;
  x0 += x1; x1 = rotl32(x1, 15); x1 ^= x0;
  x0 += x1; x1 = rotl32(x1, 26); x1 ^= x0;
  x0 += x1; x1 = rotl32(x1, 6);  x1 ^= x0;
  x0 += ks1; x1 += ks2 + 1u;
  x0 += x1; x1 = rotl32(x1, 17); x1 ^= x0;
  x0 += x1; x1 = rotl32(x1, 29); x1 ^= x0;
  x0 += x1; x1 = rotl32(x1, 16); x1 ^= x0;
  x0 += x1; x1 = rotl32(x1, 24); x1 ^= x0;
  x0 += ks2; x1 += ks0 + 2u;
  x0 += x1; x1 = rotl32(x1, 13); x1 ^= x0;
  x0 += x1; x1 = rotl32(x1, 15); x1 ^= x0;
  x0 += x1; x1 = rotl32(x1, 26); x1 ^= x0;
  x0 += x1; x1 = rotl32(x1, 6);  x1 ^= x0;
  x0 += ks0; x1 += ks1 + 3u;
  x0 += x1; x1 = rotl32(x1, 17); x1 ^= x0;
  x0 += x1; x1 = rotl32(x1, 29); x1 ^= x0;
  x0 += x1; x1 = rotl32(x1, 16); x1 ^= x0;
  x0 += x1; x1 = rotl32(x1, 24); x1 ^= x0;
  x0 += ks1; x1 += ks2 + 4u;
  x0 += x1; x1 = rotl32(x1, 13); x1 ^= x0;
  x0 += x1; x1 = rotl32(x1, 15); x1 ^= x0;
  x0 += x1; x1 = rotl32(x1, 26); x1 ^= x0;
  x0 += x1; x1 = rotl32(x1, 6);  x1 ^= x0;
  x0 += ks2; x1 += ks0 + 5u;
}

__global__ void idx_kernel(int* __restrict__ idxb, int n, int layer, int mask) {
  int e = blockIdx.x * 256 + threadIdx.x;
  if (e >= n) return;
  // fold_in(key(42), layer): folded = block(key=(0,42), x=(0,layer))
  uint32_t f0 = 0u, f1 = (uint32_t)layer;
  tf_block(0u, 42u, f0, f1);
#if IDX_VARIANT == 1
  // split(folded)[1] = both words of block(folded, (0,1))
  uint32_t s0 = 0u, s1 = 1u;
  tf_block(f0, f1, s0, s1);
  // lower_bits[e] = out0 ^ out1 of block(k2, (0, e))
  uint32_t x0 = 0u, x1 = (uint32_t)e;
  tf_block(s0, s1, x0, x1);
  uint32_t bits = x0 ^ x1;
#else
  // legacy split: counts = iota(4) -> blocks (0,2) and (1,3); k2 = (out1(0,2), out1(1,3))
  uint32_t a0 = 0u, a1 = 2u;
  tf_block(f0, f1, a0, a1);
  uint32_t b0 = 1u, b1 = 3u;
  tf_block(f0, f1, b0, b1);
  int half = n >> 1;
  int i = (e < half) ? e : (e - half);
  uint32_t x0 = (uint32_t)i, x1 = (uint32_t)(half + i);
  tf_block(a1, b1, x0, x1);
  uint32_t bits = (e < half) ? x0 : x1;
#endif
  idxb[e] = (int)(bits & (uint32_t)mask);
}

// ---------------------------------------------------------------- GEMM
// C[m,n] = act( sum_k A[m,k]*W[n,k] + bias[n] + (HASR ? R[m,n] : 0) )
__device__ __forceinline__ float gelu_f(float v) {
  return 0.5f * v * (1.0f + erff(v * 0.7071067811865476f));
}

template <int ACT, int HASR>
__global__ __launch_bounds__(256) void gemm_kernel(
    const float* __restrict__ A, const float* __restrict__ W,
    const float* __restrict__ bias, const float* Rres, float* C, int N, int K) {
  __shared__ float As[16][64];
  __shared__ float Ws[16][64];
  int tid = threadIdx.x;
  int row0 = blockIdx.y * 64, col0 = blockIdx.x * 64;
  int lr = tid >> 2;          // 0..63
  int lk = (tid & 3) << 2;    // 0,4,8,12
  int tx = tid & 15, ty = tid >> 4;
  float acc[4][4] = {};
  const float* Ap = A + (size_t)(row0 + lr) * K + lk;
  const float* Wp = W + (size_t)(col0 + lr) * K + lk;
  for (int k0 = 0; k0 < K; k0 += 16) {
    float4 a4 = *(const float4*)(Ap + k0);
    float4 w4 = *(const float4*)(Wp + k0);
    As[lk + 0][lr] = a4.x; As[lk + 1][lr] = a4.y;
    As[lk + 2][lr] = a4.z; As[lk + 3][lr] = a4.w;
    Ws[lk + 0][lr] = w4.x; Ws[lk + 1][lr] = w4.y;
    Ws[lk + 2][lr] = w4.z; Ws[lk + 3][lr] = w4.w;
    __syncthreads();
#pragma unroll
    for (int k = 0; k < 16; k++) {
      float av[4], wv[4];
#pragma unroll
      for (int i = 0; i < 4; i++) av[i] = As[k][ty * 4 + i];
#pragma unroll
      for (int j = 0; j < 4; j++) wv[j] = Ws[k][tx * 4 + j];
#pragma unroll
      for (int i = 0; i < 4; i++)
#pragma unroll
        for (int j = 0; j < 4; j++) acc[i][j] += av[i] * wv[j];
    }
    __syncthreads();
  }
#pragma unroll
  for (int i = 0; i < 4; i++) {
    int m = row0 + ty * 4 + i;
    int c0 = col0 + tx * 4;
    float4 outv;
    float* po = (float*)&outv;
#pragma unroll
    for (int j = 0; j < 4; j++) {
      float v = acc[i][j] + bias[c0 + j];
      if (HASR) v += Rres[(size_t)m * N + c0 + j];
      if (ACT == 1) v = gelu_f(v);
      po[j] = v;
    }
    *(float4*)(C + (size_t)m * N + c0) = outv;
  }
}

// ---------------------------------------------------------------- token conv + pos embed
__global__ void tokpe_kernel(const float* __restrict__ xe,
                             const float* __restrict__ w,
                             float* __restrict__ out, int S) {
  int gid = blockIdx.x * 256 + threadIdx.x;  // B*S*512
  int o = gid & 511;
  int bt = gid >> 9;
  int t = bt % S, b = bt / S;
  float acc = 0.f;
#pragma unroll
  for (int ww = 0; ww < 3; ww++) {
    int tt = t - 1 + ww;
    tt = (tt < 0) ? tt + S : (tt >= S ? tt - S : tt);
    const float* xr = xe + ((size_t)(b * S + tt)) * 7;
#pragma unroll
    for (int i = 0; i < 7; i++) acc += xr[i] * w[o * 21 + i * 3 + ww];
  }
  int i2 = o >> 1;
  float dv = expf((float)(2 * i2) * (-9.210340371976184f / 512.0f));
  float ang = (float)t * dv;
  acc += (o & 1) ? cosf(ang) : sinf(ang);
  out[gid] = acc;
}

// ---------------------------------------------------------------- M score (per batch)
__global__ __launch_bounds__(256) void mscore_kernel(
    const float* __restrict__ qb, const float* __restrict__ kb,
    const int* __restrict__ idxb, float* __restrict__ Mout, int L, int U) {
  int gid = blockIdx.x * 256 + threadIdx.x;  // 8*L  (h*L + t)
  int t = gid % L;
  int h = gid / L;
  const float4* qr = (const float4*)(qb + (size_t)t * DMODEL + h * HD);
  float4 qv[16];
#pragma unroll
  for (int i = 0; i < 16; i++) qv[i] = qr[i];
  float mx = -3.4e38f, sm = 0.f;
  for (int j = 0; j < U; j++) {
    int kr = idxb[t * U + j];
    const float4* kp = (const float4*)(kb + (size_t)kr * DMODEL + h * HD);
    float dot = 0.f;
#pragma unroll
    for (int i = 0; i < 16; i++) {
      float4 kv = kp[i];
      dot += qv[i].x * kv.x + qv[i].y * kv.y + qv[i].z * kv.z + qv[i].w * kv.w;
    }
    mx = fmaxf(mx, dot);
    sm += dot;
  }
  Mout[gid] = mx - sm / (float)L;
}

// ---------------------------------------------------------------- top-k (per head)
__global__ __launch_bounds__(256) void topk_kernel(const float* __restrict__ Mv,
                                                   int* __restrict__ topb, int L,
                                                   int u) {
  __shared__ float vals[2048];
  __shared__ float rv[256];
  __shared__ int ri[256];
  int h = blockIdx.x, tid = threadIdx.x;
  for (int t = tid; t < L; t += 256) vals[t] = Mv[(size_t)h * L + t];
  __syncthreads();
  for (int r = 0; r < u; r++) {
    float bv = -3.4e38f;
    int bi = 0x7fffffff;
    for (int t = tid; t < L; t += 256) {
      float v = vals[t];
      if (v > bv) { bv = v; bi = t; }
    }
    rv[tid] = bv; ri[tid] = bi;
    __syncthreads();
    for (int s = 128; s > 0; s >>= 1) {
      if (tid < s) {
        if (rv[tid + s] > rv[tid] ||
            (rv[tid + s] == rv[tid] && ri[tid + s] < ri[tid])) {
          rv[tid] = rv[tid + s];
          ri[tid] = ri[tid + s];
        }
      }
      __syncthreads();
    }
    if (tid == 0) {
      topb[h * u + r] = ri[0];
      vals[ri[0]] = -3.4e38f;
    }
    __syncthreads();
  }
}

// ---------------------------------------------------------------- gather selected q rows
__global__ void gatherq_kernel(const float* __restrict__ qb,
                               const int* __restrict__ topb,
                               float* __restrict__ qsel, int u) {
  int blk = blockIdx.x;  // 8*u  (h*u + r)
  int h = blk / u;
  int tq = topb[blk];
  qsel[blk * HD + threadIdx.x] = qb[(size_t)tq * DMODEL + h * HD + threadIdx.x];
}

// ---------------------------------------------------------------- mean of v over L (per batch)
__global__ void meanv_kernel(const float* __restrict__ vb, float* __restrict__ mv,
                             int L) {
  int h = blockIdx.x;  // 8
  int d = threadIdx.x; // 64
  const float* base = vb + h * HD + d;
  float s = 0.f;
  for (int t = 0; t < L; t++) s += base[(size_t)t * DMODEL];
  mv[h * HD + d] = s / (float)L;
}

__global__ void ctxfill_kernel(const float* __restrict__ mv,
                               float* __restrict__ ctx) {
  int gid = blockIdx.x * 256 + threadIdx.x;  // L*512
  ctx[gid] = mv[gid & 511];
}

// ---------------------------------------------------------------- full attention for selected rows
__global__ __launch_bounds__(256) void attnrow_kernel(
    const float* __restrict__ qsel, const float* __restrict__ kb,
    const float* __restrict__ vb, const int* __restrict__ topb,
    float* __restrict__ ctx, int L, int u) {
  __shared__ float qs[64];
  __shared__ float sc[2048];
  __shared__ float red[256];
  __shared__ float part[4][64];
  int blk = blockIdx.x;  // 8*u (h*u + r)
  int h = blk / u;
  int tid = threadIdx.x;
  int tq = topb[blk];
  if (tid < 64) qs[tid] = qsel[blk * HD + tid];
  __syncthreads();
  float lmax = -3.4e38f;
  for (int j = tid; j < L; j += 256) {
    const float* kp = kb + (size_t)j * DMODEL + h * HD;
    float dot = 0.f;
#pragma unroll
    for (int d = 0; d < 64; d++) dot += qs[d] * kp[d];
    dot *= 0.125f;  // 1/sqrt(64)
    sc[j] = dot;
    lmax = fmaxf(lmax, dot);
  }
  red[tid] = lmax;
  __syncthreads();
  for (int s = 128; s > 0; s >>= 1) {
    if (tid < s) red[tid] = fmaxf(red[tid], red[tid + s]);
    __syncthreads();
  }
  float m = red[0];
  __syncthreads();
  float lsum = 0.f;
  for (int j = tid; j < L; j += 256) {
    float p = expf(sc[j] - m);
    sc[j] = p;
    lsum += p;
  }
  red[tid] = lsum;
  __syncthreads();
  for (int s = 128; s > 0; s >>= 1) {
    if (tid < s) red[tid] += red[tid + s];
    __syncthreads();
  }
  float S = red[0];
  int g = tid >> 6, d = tid & 63;
  float pa = 0.f;
  for (int j = g; j < L; j += 4)
    pa += sc[j] * vb[(size_t)j * DMODEL + h * HD + d];
  part[g][d] = pa;
  __syncthreads();
  if (tid < 64) {
    float o = (part[0][tid] + part[1][tid] + part[2][tid] + part[3][tid]) / S;
    ctx[(size_t)tq * DMODEL + h * HD + tid] = o;
  }
}

// ---------------------------------------------------------------- layernorm (512 cols)
__global__ __launch_bounds__(256) void ln_kernel(const float* __restrict__ X,
                                                 const float* __restrict__ g,
                                                 const float* __restrict__ bta,
                                                 float* __restrict__ Y) {
  __shared__ float red[256];
  int row = blockIdx.x, tid = threadIdx.x;
  size_t base = (size_t)row * DMODEL;
  float x0 = X[base + tid], x1 = X[base + tid + 256];
  red[tid] = x0 + x1;
  __syncthreads();
  for (int s = 128; s > 0; s >>= 1) {
    if (tid < s) red[tid] += red[tid + s];
    __syncthreads();
  }
  float mean = red[0] * (1.0f / 512.0f);
  __syncthreads();
  float d0 = x0 - mean, d1 = x1 - mean;
  red[tid] = d0 * d0 + d1 * d1;
  __syncthreads();
  for (int s = 128; s > 0; s >>= 1) {
    if (tid < s) red[tid] += red[tid + s];
    __syncthreads();
  }
  float inv = 1.0f / sqrtf(red[0] * (1.0f / 512.0f) + 1e-5f);
  Y[base + tid] = d0 * inv * g[tid] + bta[tid];
  Y[base + tid + 256] = d1 * inv * g[tid + 256] + bta[tid + 256];
}

// ---------------------------------------------------------------- distil helpers
__global__ void packw_kernel(const float* __restrict__ dw, float* __restrict__ wp) {
  int gid = blockIdx.x * 256 + threadIdx.x;  // 512*1536
  int o = gid / 1536;
  int kk = gid - o * 1536;
  int ww = kk / 512;
  int c = kk - ww * 512;
  wp[gid] = dw[((size_t)o * 512 + c) * 3 + ww];
}

__global__ void im2col_kernel(const float* __restrict__ x, float* __restrict__ X3,
                              int L, int r0) {
  int gid = blockIdx.x * 256 + threadIdx.x;  // CR*1536
  int kk = gid % 1536;
  int row = r0 + gid / 1536;
  int t = row % L, b = row / L;
  int ww = kk / 512;
  int c = kk - ww * 512;
  int tt = t - 1 + ww;
  tt = (tt < 0) ? tt + L : (tt >= L ? tt - L : tt);
  X3[gid] = x[((size_t)(b * L + tt)) * DMODEL + c];
}

__global__ __launch_bounds__(256) void bnpart_kernel(const float* __restrict__ z,
                                                     float* __restrict__ psum,
                                                     float* __restrict__ psq,
                                                     int rowsPer) {
  int blk = blockIdx.x, tid = threadIdx.x;
  size_t r0 = (size_t)blk * rowsPer;
  float s0 = 0, q0 = 0, s1 = 0, q1 = 0;
  for (int r = 0; r < rowsPer; r++) {
    const float* zp = z + (r0 + r) * DMODEL;
    float a = zp[tid];
    s0 += a; q0 += a * a;
    float c = zp[tid + 256];
    s1 += c; q1 += c * c;
  }
  psum[blk * DMODEL + tid] = s0;
  psum[blk * DMODEL + tid + 256] = s1;
  psq[blk * DMODEL + tid] = q0;
  psq[blk * DMODEL + tid + 256] = q1;
}

__global__ void bnfin_kernel(const float* __restrict__ psum,
                             const float* __restrict__ psq, float* __restrict__ mu,
                             float* __restrict__ var, int nb, int Rtot) {
  int c = blockIdx.x * 256 + threadIdx.x;  // 512 total
  float s = 0, q = 0;
  for (int b = 0; b < nb; b++) {
    s += psum[b * DMODEL + c];
    q += psq[b * DMODEL + c];
  }
  float m = s / (float)Rtot;
  mu[c] = m;
  var[c] = fmaxf(q / (float)Rtot - m * m, 0.f);
}

__global__ void bnpool_kernel(const float* __restrict__ z,
                              const float* __restrict__ mu,
                              const float* __restrict__ var,
                              const float* __restrict__ g,
                              const float* __restrict__ bta,
                              float* __restrict__ out, int L) {
  int gid = blockIdx.x * 256 + threadIdx.x;  // B*(L/2)*512
  int c = gid & 511;
  int bt = gid >> 9;
  int L2 = L >> 1;
  int t2 = bt % L2, b = bt / L2;
  float m = mu[c];
  float inv = 1.0f / sqrtf(var[c] + 1e-5f);
  float gg = g[c], bb = bta[c];
  float best = -3.4e38f;
#pragma unroll
  for (int ww = 0; ww < 3; ww++) {
    int t = 2 * t2 - 1 + ww;
    if (t < 0 || t >= L) continue;
    float yv = (z[((size_t)(b * L + t)) * DMODEL + c] - m) * inv * gg + bb;
    yv = (yv > 0.f) ? yv : expm1f(yv);
    best = fmaxf(best, yv);
  }
  out[gid] = best;
}

// ---------------------------------------------------------------- final projection (512 -> 7)
__global__ __launch_bounds__(64) void end_kernel(const float* __restrict__ xn,
                                                 const float* __restrict__ ew,
                                                 const float* __restrict__ eb,
                                                 float* __restrict__ out) {
  __shared__ float xs[512];
  __shared__ float red[64];
  int row = blockIdx.x, tid = threadIdx.x;
#pragma unroll
  for (int i = 0; i < 8; i++) xs[tid + 64 * i] = xn[(size_t)row * DMODEL + tid + 64 * i];
  __syncthreads();
  for (int c = 0; c < 7; c++) {
    float p = 0.f;
    for (int d = tid; d < 512; d += 64) p += xs[d] * ew[c * DMODEL + d];
    red[tid] = p;
    __syncthreads();
    for (int s = 32; s > 0; s >>= 1) {
      if (tid < s) red[tid] += red[tid + s];
      __syncthreads();
    }
    if (tid == 0) out[row * 7 + c] = red[0] + eb[c];
    __syncthreads();
  }
}

// ---------------------------------------------------------------- host
extern "C" void kernel_launch(void* const* d_in, const int* in_sizes, int n_in,
                              void* d_out, int out_size, void* d_ws,
                              size_t ws_size, hipStream_t stream) {
  (void)in_sizes; (void)n_in; (void)out_size; (void)ws_size;
  const float* x_enc = (const float*)d_in[0];
  const float* tok_w = (const float*)d_in[1];
  const float* Wq = (const float*)d_in[2];
  const float* bq = (const float*)d_in[3];
  const float* Wk = (const float*)d_in[4];
  const float* bk = (const float*)d_in[5];
  const float* Wv = (const float*)d_in[6];
  const float* bv = (const float*)d_in[7];
  const float* Wo = (const float*)d_in[8];
  const float* bo = (const float*)d_in[9];
  const float* w1 = (const float*)d_in[10];
  const float* b1 = (const float*)d_in[11];
  const float* w2 = (const float*)d_in[12];
  const float* b2 = (const float*)d_in[13];
  const float* g1 = (const float*)d_in[14];
  const float* be1 = (const float*)d_in[15];
  const float* g2 = (const float*)d_in[16];
  const float* be2 = (const float*)d_in[17];
  const float* dw = (const float*)d_in[18];
  const float* db = (const float*)d_in[19];
  const float* bng = (const float*)d_in[20];
  const float* bnb = (const float*)d_in[21];
  const float* lnfg = (const float*)d_in[22];
  const float* lnfb = (const float*)d_in[23];
  const float* endw = (const float*)d_in[24];
  const float* endb = (const float*)d_in[25];
  float* out = (float*)d_out;
  char* ws = (char*)d_ws;

  // ---- workspace arena (~105 MB total) ----
  size_t o = 0;
  float* buf0 = (float*)(ws + o); o += (size_t)16384 * 512 * 4;  // x
  float* buf1 = (float*)(ws + o); o += (size_t)16384 * 512 * 4;  // x1 / z
  float* qb   = (float*)(ws + o); o += (size_t)2048 * 512 * 4;
  float* kb   = (float*)(ws + o); o += (size_t)2048 * 512 * 4;
  float* vb   = (float*)(ws + o); o += (size_t)2048 * 512 * 4;
  float* ctxb = (float*)(ws + o); o += (size_t)2048 * 512 * 4;
  float* CH   = (float*)(ws + o); o += (size_t)2048 * 2048 * 4; // chunk scratch
  float* wpack= (float*)(ws + o); o += (size_t)512 * 1536 * 4;
  float* Mb   = (float*)(ws + o); o += (size_t)8 * 2048 * 4;
  int*   idxb = (int*)(ws + o);   o += (size_t)2048 * 24 * 4;
  int*   topb = (int*)(ws + o);   o += 1024;
  float* qsel = (float*)(ws + o); o += (size_t)8 * 24 * 64 * 4;
  float* mv   = (float*)(ws + o); o += (size_t)8 * 64 * 4;
  float* psum = (float*)(ws + o); o += (size_t)128 * 512 * 4;
  float* psq  = (float*)(ws + o); o += (size_t)128 * 512 * 4;
  float* muv  = (float*)(ws + o); o += 2048;
  float* varv = (float*)(ws + o); o += 2048;

  const int B = 8;
  const int S = 2048;
  const int CHROWS = 2048;  // FFN/im2col chunk rows
  tokpe_kernel<<<B * S * DMODEL / 256, 256, 0, stream>>>(x_enc, tok_w, buf0, S);

  int L = S;
  const int Uarr[3] = {24, 21, 21};  // 3*ceil(ln(L)) for 2048,1024,512
  for (int l = 0; l < 3; l++) {
    int U = Uarr[l];
    int u = Uarr[l];
    int BL = B * L;
    idx_kernel<<<(L * U + 255) / 256, 256, 0, stream>>>(idxb, L * U, l, L - 1);

    // ---- attention, per batch ----
    dim3 gq(DMODEL / 64, L / 64);
    for (int b = 0; b < B; b++) {
      const float* xb = buf0 + (size_t)b * L * DMODEL;
      gemm_kernel<0, 0><<<gq, 256, 0, stream>>>(
          xb, Wq + (size_t)l * DMODEL * DMODEL, bq + l * DMODEL, nullptr, qb,
          DMODEL, DMODEL);
      gemm_kernel<0, 0><<<gq, 256, 0, stream>>>(
          xb, Wk + (size_t)l * DMODEL * DMODEL, bk + l * DMODEL, nullptr, kb,
          DMODEL, DMODEL);
      gemm_kernel<0, 0><<<gq, 256, 0, stream>>>(
          xb, Wv + (size_t)l * DMODEL * DMODEL, bv + l * DMODEL, nullptr, vb,
          DMODEL, DMODEL);
      mscore_kernel<<<8 * L / 256, 256, 0, stream>>>(qb, kb, idxb, Mb, L, U);
      topk_kernel<<<8, 256, 0, stream>>>(Mb, topb, L, u);
      gatherq_kernel<<<8 * u, 64, 0, stream>>>(qb, topb, qsel, u);
      meanv_kernel<<<8, 64, 0, stream>>>(vb, mv, L);
      ctxfill_kernel<<<L * DMODEL / 256, 256, 0, stream>>>(mv, ctxb);
      attnrow_kernel<<<8 * u, 256, 0, stream>>>(qsel, kb, vb, topb, ctxb, L, u);
      // x1_b = x_b + ctx_b @ Wo^T + bo
      gemm_kernel<0, 1><<<gq, 256, 0, stream>>>(
          ctxb, Wo + (size_t)l * DMODEL * DMODEL, bo + l * DMODEL, xb,
          buf1 + (size_t)b * L * DMODEL, DMODEL, DMODEL);
    }
    // xa = LN1(x1)  -> buf0
    ln_kernel<<<BL, 256, 0, stream>>>(buf1, g1 + l * DMODEL, be1 + l * DMODEL, buf0);
    // FFN, chunked over rows: z = xa + gelu(xa@w1^T+b1)@w2^T+b2 -> buf1
    for (int r0 = 0; r0 < BL; r0 += CHROWS) {
      dim3 g1d(2048 / 64, CHROWS / 64);
      gemm_kernel<1, 0><<<g1d, 256, 0, stream>>>(
          buf0 + (size_t)r0 * DMODEL, w1 + (size_t)l * 2048 * DMODEL, b1 + l * 2048,
          nullptr, CH, 2048, DMODEL);
      dim3 g2d(DMODEL / 64, CHROWS / 64);
      gemm_kernel<0, 1><<<g2d, 256, 0, stream>>>(
          CH, w2 + (size_t)l * DMODEL * 2048, b2 + l * DMODEL,
          buf0 + (size_t)r0 * DMODEL, buf1 + (size_t)r0 * DMODEL, DMODEL, 2048);
    }
    // x = LN2(z) -> buf0
    ln_kernel<<<BL, 256, 0, stream>>>(buf1, g2 + l * DMODEL, be2 + l * DMODEL, buf0);

    if (l < 2) {
      packw_kernel<<<512 * 1536 / 256, 256, 0, stream>>>(
          dw + (size_t)l * DMODEL * DMODEL * 3, wpack);
      for (int r0 = 0; r0 < BL; r0 += CHROWS) {
        im2col_kernel<<<CHROWS * 1536 / 256, 256, 0, stream>>>(buf0, CH, L, r0);
        dim3 gc(DMODEL / 64, CHROWS / 64);
        gemm_kernel<0, 0><<<gc, 256, 0, stream>>>(
            CH, wpack, db + l * DMODEL, nullptr, buf1 + (size_t)r0 * DMODEL,
            DMODEL, 1536);
      }
      int nb = BL / 128;
      bnpart_kernel<<<nb, 256, 0, stream>>>(buf1, psum, psq, 128);
      bnfin_kernel<<<2, 256, 0, stream>>>(psum, psq, muv, varv, nb, BL);
      bnpool_kernel<<<(BL / 2) * DMODEL / 256, 256, 0, stream>>>(
          buf1, muv, varv, bng + l * DMODEL, bnb + l * DMODEL, buf0, L);
      L >>= 1;
    }
  }
  int BL = B * L;  // 8*512
  ln_kernel<<<BL, 256, 0, stream>>>(buf0, lnfg, lnfb, buf1);
  end_kernel<<<BL, 64, 0, stream>>>(buf1, endw, endb, out);
}

// Round 4
// 10962.298 us; speedup vs baseline: 1.5895x; 1.5895x over previous
//
#include <hip/hip_runtime.h>
#include <cstdint>
#include <cstddef>

#define DMODEL 512
#define NHEAD 8
#define HD 64

// ---------------------------------------------------------------- threefry
__device__ __forceinline__ uint32_t rotl32(uint32_t x, int r) {
  return (x << r) | (x >> (32 - r));
}

__device__ __forceinline__ void tf_block(uint32_t k0, uint32_t k1,
                                         uint32_t& x0, uint32_t& x1) {
  uint32_t ks0 = k0, ks1 = k1, ks2 = k0 ^ k1 ^ 0x1BD11BDAu;
  x0 += ks0; x1 += ks1;
  x0 += x1; x1 = rotl32(x1, 13); x1 ^= x0;
  x0 += x1; x1 = rotl32(x1, 15); x1 ^= x0;
  x0 += x1; x1 = rotl32(x1, 26); x1 ^= x0;
  x0 += x1; x1 = rotl32(x1, 6);  x1 ^= x0;
  x0 += ks1; x1 += ks2 + 1u;
  x0 += x1; x1 = rotl32(x1, 17); x1 ^= x0;
  x0 += x1; x1 = rotl32(x1, 29); x1 ^= x0;
  x0 += x1; x1 = rotl32(x1, 16); x1 ^= x0;
  x0 += x1; x1 = rotl32(x1, 24); x1 ^= x0;
  x0 += ks2; x1 += ks0 + 2u;
  x0 += x1; x1 = rotl32(x1, 13); x1 ^= x0;
  x0 += x1; x1 = rotl32(x1, 15); x1 ^= x0;
  x0 += x1; x1 = rotl32(x1, 26); x1 ^= x0;
  x0 += x1; x1 = rotl32(x1, 6);  x1 ^= x0;
  x0 += ks0; x1 += ks1 + 3u;
  x0 += x1; x1 = rotl32(x1, 17); x1 ^= x0;
  x0 += x1; x1 = rotl32(x1, 29); x1 ^= x0;
  x0 += x1; x1 = rotl32(x1, 16); x1 ^= x0;
  x0 += x1; x1 = rotl32(x1, 24); x1 ^= x0;
  x0 += ks1; x1 += ks2 + 4u;
  x0 += x1; x1 = rotl32(x1, 13); x1 ^= x0;
  x0 += x1; x1 = rotl32(x1, 15); x1 ^= x0;
  x0 += x1; x1 = rotl32(x1, 26); x1 ^= x0;
  x0 += x1; x1 = rotl32(x1, 6);  x1 ^= x0;
  x0 += ks2; x1 += ks0 + 5u;
}

__global__ void idx_kernel(int* __restrict__ idxb, int n, int layer, int mask) {
  int e = blockIdx.x * 256 + threadIdx.x;
  if (e >= n) return;
  uint32_t f0 = 0u, f1 = (uint32_t)layer;
  tf_block(0u, 42u, f0, f1);
  // split(folded)[1] = both words of block(folded, (0,1))
  uint32_t s0 = 0u, s1 = 1u;
  tf_block(f0, f1, s0, s1);
  uint32_t x0 = 0u, x1 = (uint32_t)e;
  tf_block(s0, s1, x0, x1);
  uint32_t bits = x0 ^ x1;
  idxb[e] = (int)(bits & (uint32_t)mask);
}

// ---------------------------------------------------------------- GEMM v2
// C[m,n] = act( sum_k A[m,k]*W[n,k] + bias[n] + (HASR ? R[m,n] : 0) )
// CONV=1: A is x (rows BL x 512); logical A[r][k] = x[b*L + ((t-1+w)&Lmask)][k&511],
//         w = k>>9, r = b*L + t. Requires K=1536, L pow2.
__device__ __forceinline__ float gelu_f(float v) {
  return 0.5f * v * (1.0f + erff(v * 0.7071067811865476f));
}

template <int ACT, int HASR, int CONV>
__global__ __launch_bounds__(256) void gemm64(
    const float* __restrict__ A, const float* __restrict__ W,
    const float* __restrict__ bias, const float* Rres, float* __restrict__ C,
    int N, int K, int Lmask) {
  __shared__ float As[2][32][66];
  __shared__ float Ws[2][32][66];
  const int tid = threadIdx.x;
  const int row0 = blockIdx.y * 64, col0 = blockIdx.x * 64;
  const int sm = tid >> 2;          // 0..63
  const int sk = (tid & 3) << 3;    // 0,8,16,24
  const int tx = tid & 15, ty = tid >> 4;
  const int arow = row0 + sm;
  const float* Wp = W + (size_t)(col0 + sm) * K + sk;
  const float* Ap = A + (size_t)arow * K + sk;  // non-conv
  int tcv = 0, bbase = 0;
  if (CONV) { tcv = arow & Lmask; bbase = arow & ~Lmask; }
  float4 ra0, ra1, rw0, rw1;
  float acc[4][4] = {};
  const int T = K >> 5;

  {
    const float* ap;
    if (CONV) {
      int src = bbase | ((tcv - 1) & Lmask);  // k0=0 -> w=0
      ap = A + (size_t)src * 512 + sk;
    } else {
      ap = Ap;
    }
    ra0 = *(const float4*)(ap);
    ra1 = *(const float4*)(ap + 4);
    rw0 = *(const float4*)(Wp);
    rw1 = *(const float4*)(Wp + 4);
  }

  for (int it = 0; it < T; ++it) {
    const int buf = it & 1;
#pragma unroll
    for (int j = 0; j < 4; j++) {
      As[buf][sk + j][sm] = ((float*)&ra0)[j];
      As[buf][sk + 4 + j][sm] = ((float*)&ra1)[j];
      Ws[buf][sk + j][sm] = ((float*)&rw0)[j];
      Ws[buf][sk + 4 + j][sm] = ((float*)&rw1)[j];
    }
    __syncthreads();
    if (it + 1 < T) {
      const int k0 = (it + 1) << 5;
      const float* ap;
      if (CONV) {
        int w = k0 >> 9;
        int src = bbase | ((tcv - 1 + w) & Lmask);
        ap = A + (size_t)src * 512 + ((k0 & 511) + sk);
      } else {
        ap = Ap + k0;
      }
      ra0 = *(const float4*)(ap);
      ra1 = *(const float4*)(ap + 4);
      rw0 = *(const float4*)(Wp + k0);
      rw1 = *(const float4*)(Wp + k0 + 4);
    }
#pragma unroll
    for (int k = 0; k < 32; k++) {
      float av[4], wv[4];
#pragma unroll
      for (int i = 0; i < 4; i++) av[i] = As[buf][k][ty * 4 + i];
#pragma unroll
      for (int j = 0; j < 4; j++) wv[j] = Ws[buf][k][tx * 4 + j];
#pragma unroll
      for (int i = 0; i < 4; i++)
#pragma unroll
        for (int j = 0; j < 4; j++) acc[i][j] += av[i] * wv[j];
    }
  }

#pragma unroll
  for (int i = 0; i < 4; i++) {
    const int m = row0 + ty * 4 + i;
    const int c0 = col0 + tx * 4;
    float4 outv;
    float* po = (float*)&outv;
#pragma unroll
    for (int j = 0; j < 4; j++) {
      float v = acc[i][j] + bias[c0 + j];
      if (HASR) v += Rres[(size_t)m * N + c0 + j];
      if (ACT == 1) v = gelu_f(v);
      po[j] = v;
    }
    *(float4*)(C + (size_t)m * N + c0) = outv;
  }
}

// ---------------------------------------------------------------- token conv + pos embed
__global__ void tokpe_kernel(const float* __restrict__ xe,
                             const float* __restrict__ w,
                             float* __restrict__ out, int S) {
  int gid = blockIdx.x * 256 + threadIdx.x;  // B*S*512
  int o = gid & 511;
  int bt = gid >> 9;
  int t = bt % S, b = bt / S;
  float acc = 0.f;
#pragma unroll
  for (int ww = 0; ww < 3; ww++) {
    int tt = t - 1 + ww;
    tt = (tt < 0) ? tt + S : (tt >= S ? tt - S : tt);
    const float* xr = xe + ((size_t)(b * S + tt)) * 7;
#pragma unroll
    for (int i = 0; i < 7; i++) acc += xr[i] * w[o * 21 + i * 3 + ww];
  }
  int i2 = o >> 1;
  float dv = expf((float)(2 * i2) * (-9.210340371976184f / 512.0f));
  float ang = (float)t * dv;
  acc += (o & 1) ? cosf(ang) : sinf(ang);
  out[gid] = acc;
}

// ---------------------------------------------------------------- weight packs
__global__ void packqkv_kernel(const float* __restrict__ Wq,
                               const float* __restrict__ Wk,
                               const float* __restrict__ Wv,
                               const float* __restrict__ bq,
                               const float* __restrict__ bk,
                               const float* __restrict__ bv,
                               float* __restrict__ wqkv,
                               float* __restrict__ bqkv) {
  int gid = blockIdx.x * 256 + threadIdx.x;  // 1536*512
  int n = gid >> 9, k = gid & 511;
  const float* src = (n < 512) ? Wq : (n < 1024 ? Wk : Wv);
  wqkv[gid] = src[(size_t)(n & 511) * 512 + k];
  if (gid < 1536) {
    const float* bs = (gid < 512) ? bq : (gid < 1024 ? bk : bv);
    bqkv[gid] = bs[gid & 511];
  }
}

__global__ void packw_kernel(const float* __restrict__ dw, float* __restrict__ wp) {
  int gid = blockIdx.x * 256 + threadIdx.x;  // 512*1536
  int o = gid / 1536;
  int kk = gid - o * 1536;
  int ww = kk / 512;
  int c = kk - ww * 512;
  wp[gid] = dw[((size_t)o * 512 + c) * 3 + ww];
}

// ---------------------------------------------------------------- M score (per batch; qkv packed stride 1536)
__global__ __launch_bounds__(256) void mscore_kernel(
    const float* __restrict__ qkv, const int* __restrict__ idxb,
    float* __restrict__ Mout, int L, int U) {
  int gid = blockIdx.x * 256 + threadIdx.x;  // 8*L  (h*L + t)
  int t = gid % L;
  int h = gid / L;
  const float4* qr = (const float4*)(qkv + (size_t)t * 1536 + h * HD);
  float4 qv[16];
#pragma unroll
  for (int i = 0; i < 16; i++) qv[i] = qr[i];
  float mx = -3.4e38f, sm = 0.f;
  for (int j = 0; j < U; j++) {
    int kr = idxb[t * U + j];
    const float4* kp = (const float4*)(qkv + (size_t)kr * 1536 + 512 + h * HD);
    float dot = 0.f;
#pragma unroll
    for (int i = 0; i < 16; i++) {
      float4 kv = kp[i];
      dot += qv[i].x * kv.x + qv[i].y * kv.y + qv[i].z * kv.z + qv[i].w * kv.w;
    }
    mx = fmaxf(mx, dot);
    sm += dot;
  }
  Mout[gid] = mx - sm / (float)L;
}

// ---------------------------------------------------------------- top-k (per head)
__global__ __launch_bounds__(256) void topk_kernel(const float* __restrict__ Mv,
                                                   int* __restrict__ topb, int L,
                                                   int u) {
  __shared__ float vals[2048];
  __shared__ float rv[256];
  __shared__ int ri[256];
  int h = blockIdx.x, tid = threadIdx.x;
  for (int t = tid; t < L; t += 256) vals[t] = Mv[(size_t)h * L + t];
  __syncthreads();
  for (int r = 0; r < u; r++) {
    float bv = -3.4e38f;
    int bi = 0x7fffffff;
    for (int t = tid; t < L; t += 256) {
      float v = vals[t];
      if (v > bv) { bv = v; bi = t; }
    }
    rv[tid] = bv; ri[tid] = bi;
    __syncthreads();
    for (int s = 128; s > 0; s >>= 1) {
      if (tid < s) {
        if (rv[tid + s] > rv[tid] ||
            (rv[tid + s] == rv[tid] && ri[tid + s] < ri[tid])) {
          rv[tid] = rv[tid + s];
          ri[tid] = ri[tid + s];
        }
      }
      __syncthreads();
    }
    if (tid == 0) {
      topb[h * u + r] = ri[0];
      vals[ri[0]] = -3.4e38f;
    }
    __syncthreads();
  }
}

// ---------------------------------------------------------------- mean of v over L (per batch)
__global__ __launch_bounds__(256) void meanv_kernel(const float* __restrict__ qkv,
                                                    float* __restrict__ mv, int L) {
  __shared__ float part[4][64];
  int h = blockIdx.x;          // 8
  int tid = threadIdx.x;
  int d = tid & 63, g = tid >> 6;
  const float* base = qkv + 1024 + h * HD + d;
  float s = 0.f;
  for (int t = g; t < L; t += 4) s += base[(size_t)t * 1536];
  part[g][d] = s;
  __syncthreads();
  if (tid < 64) {
    mv[h * HD + tid] =
        (part[0][tid] + part[1][tid] + part[2][tid] + part[3][tid]) / (float)L;
  }
}

__global__ void ctxfill_kernel(const float* __restrict__ mv,
                               float* __restrict__ ctx) {
  int gid = blockIdx.x * 256 + threadIdx.x;  // L*512
  ctx[gid] = mv[gid & 511];
}

// ---------------------------------------------------------------- full attention for selected rows
__global__ __launch_bounds__(256) void attnrow_kernel(
    const float* __restrict__ qkv, const int* __restrict__ topb,
    float* __restrict__ ctx, int L, int u) {
  __shared__ float qs[64];
  __shared__ float sc[2048];
  __shared__ float red[256];
  __shared__ float part[4][64];
  int blk = blockIdx.x;  // 8*u (h*u + r)
  int h = blk / u;
  int tid = threadIdx.x;
  int tq = topb[blk];
  if (tid < 64) qs[tid] = qkv[(size_t)tq * 1536 + h * HD + tid];
  __syncthreads();
  float lmax = -3.4e38f;
  for (int j = tid; j < L; j += 256) {
    const float* kp = qkv + (size_t)j * 1536 + 512 + h * HD;
    float dot = 0.f;
#pragma unroll
    for (int d = 0; d < 64; d++) dot += qs[d] * kp[d];
    dot *= 0.125f;  // 1/sqrt(64)
    sc[j] = dot;
    lmax = fmaxf(lmax, dot);
  }
  red[tid] = lmax;
  __syncthreads();
  for (int s = 128; s > 0; s >>= 1) {
    if (tid < s) red[tid] = fmaxf(red[tid], red[tid + s]);
    __syncthreads();
  }
  float m = red[0];
  __syncthreads();
  float lsum = 0.f;
  for (int j = tid; j < L; j += 256) {
    float p = expf(sc[j] - m);
    sc[j] = p;
    lsum += p;
  }
  red[tid] = lsum;
  __syncthreads();
  for (int s = 128; s > 0; s >>= 1) {
    if (tid < s) red[tid] += red[tid + s];
    __syncthreads();
  }
  float S = red[0];
  int g = tid >> 6, d = tid & 63;
  float pa = 0.f;
  for (int j = g; j < L; j += 4)
    pa += sc[j] * qkv[(size_t)j * 1536 + 1024 + h * HD + d];
  part[g][d] = pa;
  __syncthreads();
  if (tid < 64) {
    float o = (part[0][tid] + part[1][tid] + part[2][tid] + part[3][tid]) / S;
    ctx[(size_t)tq * DMODEL + h * HD + tid] = o;
  }
}

// ---------------------------------------------------------------- layernorm (512 cols)
__global__ __launch_bounds__(256) void ln_kernel(const float* __restrict__ X,
                                                 const float* __restrict__ g,
                                                 const float* __restrict__ bta,
                                                 float* __restrict__ Y) {
  __shared__ float red[256];
  int row = blockIdx.x, tid = threadIdx.x;
  size_t base = (size_t)row * DMODEL;
  float x0 = X[base + tid], x1 = X[base + tid + 256];
  red[tid] = x0 + x1;
  __syncthreads();
  for (int s = 128; s > 0; s >>= 1) {
    if (tid < s) red[tid] += red[tid + s];
    __syncthreads();
  }
  float mean = red[0] * (1.0f / 512.0f);
  __syncthreads();
  float d0 = x0 - mean, d1 = x1 - mean;
  red[tid] = d0 * d0 + d1 * d1;
  __syncthreads();
  for (int s = 128; s > 0; s >>= 1) {
    if (tid < s) red[tid] += red[tid + s];
    __syncthreads();
  }
  float inv = 1.0f / sqrtf(red[0] * (1.0f / 512.0f) + 1e-5f);
  Y[base + tid] = d0 * inv * g[tid] + bta[tid];
  Y[base + tid + 256] = d1 * inv * g[tid + 256] + bta[tid + 256];
}

// ---------------------------------------------------------------- BN stats + pool
__global__ __launch_bounds__(256) void bnpart_kernel(const float* __restrict__ z,
                                                     float* __restrict__ psum,
                                                     float* __restrict__ psq,
                                                     int rowsPer) {
  int blk = blockIdx.x, tid = threadIdx.x;
  size_t r0 = (size_t)blk * rowsPer;
  float s0 = 0, q0 = 0, s1 = 0, q1 = 0;
  for (int r = 0; r < rowsPer; r++) {
    const float* zp = z + (r0 + r) * DMODEL;
    float a = zp[tid];
    s0 += a; q0 += a * a;
    float c = zp[tid + 256];
    s1 += c; q1 += c * c;
  }
  psum[blk * DMODEL + tid] = s0;
  psum[blk * DMODEL + tid + 256] = s1;
  psq[blk * DMODEL + tid] = q0;
  psq[blk * DMODEL + tid + 256] = q1;
}

__global__ void bnfin_kernel(const float* __restrict__ psum,
                             const float* __restrict__ psq, float* __restrict__ mu,
                             float* __restrict__ var, int nb, int Rtot) {
  int c = blockIdx.x * 256 + threadIdx.x;
  float s = 0, q = 0;
  for (int b = 0; b < nb; b++) {
    s += psum[b * DMODEL + c];
    q += psq[b * DMODEL + c];
  }
  float m = s / (float)Rtot;
  mu[c] = m;
  var[c] = fmaxf(q / (float)Rtot - m * m, 0.f);
}

__global__ void bnpool_kernel(const float* __restrict__ z,
                              const float* __restrict__ mu,
                              const float* __restrict__ var,
                              const float* __restrict__ g,
                              const float* __restrict__ bta,
                              float* __restrict__ out, int L) {
  int gid = blockIdx.x * 256 + threadIdx.x;  // B*(L/2)*512
  int c = gid & 511;
  int bt = gid >> 9;
  int L2 = L >> 1;
  int t2 = bt % L2, b = bt / L2;
  float m = mu[c];
  float inv = 1.0f / sqrtf(var[c] + 1e-5f);
  float gg = g[c], bb = bta[c];
  float best = -3.4e38f;
#pragma unroll
  for (int ww = 0; ww < 3; ww++) {
    int t = 2 * t2 - 1 + ww;
    if (t < 0 || t >= L) continue;
    float yv = (z[((size_t)(b * L + t)) * DMODEL + c] - m) * inv * gg + bb;
    yv = (yv > 0.f) ? yv : expm1f(yv);
    best = fmaxf(best, yv);
  }
  out[gid] = best;
}

// ---------------------------------------------------------------- final projection (512 -> 7)
__global__ __launch_bounds__(64) void end_kernel(const float* __restrict__ xn,
                                                 const float* __restrict__ ew,
                                                 const float* __restrict__ eb,
                                                 float* __restrict__ out) {
  __shared__ float xs[512];
  __shared__ float red[64];
  int row = blockIdx.x, tid = threadIdx.x;
#pragma unroll
  for (int i = 0; i < 8; i++) xs[tid + 64 * i] = xn[(size_t)row * DMODEL + tid + 64 * i];
  __syncthreads();
  for (int c = 0; c < 7; c++) {
    float p = 0.f;
    for (int d = tid; d < 512; d += 64) p += xs[d] * ew[c * DMODEL + d];
    red[tid] = p;
    __syncthreads();
    for (int s = 32; s > 0; s >>= 1) {
      if (tid < s) red[tid] += red[tid + s];
      __syncthreads();
    }
    if (tid == 0) out[row * 7 + c] = red[0] + eb[c];
    __syncthreads();
  }
}

// ---------------------------------------------------------------- host
extern "C" void kernel_launch(void* const* d_in, const int* in_sizes, int n_in,
                              void* d_out, int out_size, void* d_ws,
                              size_t ws_size, hipStream_t stream) {
  (void)in_sizes; (void)n_in; (void)out_size; (void)ws_size;
  const float* x_enc = (const float*)d_in[0];
  const float* tok_w = (const float*)d_in[1];
  const float* Wq = (const float*)d_in[2];
  const float* bq = (const float*)d_in[3];
  const float* Wk = (const float*)d_in[4];
  const float* bk = (const float*)d_in[5];
  const float* Wv = (const float*)d_in[6];
  const float* bv = (const float*)d_in[7];
  const float* Wo = (const float*)d_in[8];
  const float* bo = (const float*)d_in[9];
  const float* w1 = (const float*)d_in[10];
  const float* b1 = (const float*)d_in[11];
  const float* w2 = (const float*)d_in[12];
  const float* b2 = (const float*)d_in[13];
  const float* g1 = (const float*)d_in[14];
  const float* be1 = (const float*)d_in[15];
  const float* g2 = (const float*)d_in[16];
  const float* be2 = (const float*)d_in[17];
  const float* dw = (const float*)d_in[18];
  const float* db = (const float*)d_in[19];
  const float* bng = (const float*)d_in[20];
  const float* bnb = (const float*)d_in[21];
  const float* lnfg = (const float*)d_in[22];
  const float* lnfb = (const float*)d_in[23];
  const float* endw = (const float*)d_in[24];
  const float* endb = (const float*)d_in[25];
  float* out = (float*)d_out;
  char* ws = (char*)d_ws;

  // ---- workspace arena (~103 MB; known-safe <=105) ----
  size_t o = 0;
  float* buf0 = (float*)(ws + o); o += (size_t)16384 * 512 * 4;   // 32 MB
  float* buf1 = (float*)(ws + o); o += (size_t)16384 * 512 * 4;   // 32 MB
  float* qkvb = (float*)(ws + o); o += (size_t)2048 * 1536 * 4;   // 12 MB
  float* ctxb = (float*)(ws + o); o += (size_t)2048 * 512 * 4;    // 4 MB
  float* CH   = (float*)(ws + o); o += (size_t)2048 * 2048 * 4;   // 16 MB
  float* wqkv = (float*)(ws + o); o += (size_t)1536 * 512 * 4;    // 3 MB
  float* wpack= (float*)(ws + o); o += (size_t)512 * 1536 * 4;    // 3 MB
  float* bqkv = (float*)(ws + o); o += 1536 * 4;
  float* Mb   = (float*)(ws + o); o += (size_t)8 * 2048 * 4;
  int*   idxb = (int*)(ws + o);   o += (size_t)2048 * 24 * 4;
  int*   topb = (int*)(ws + o);   o += 1024;
  float* mv   = (float*)(ws + o); o += (size_t)8 * 64 * 4;
  float* psum = (float*)(ws + o); o += (size_t)128 * 512 * 4;
  float* psq  = (float*)(ws + o); o += (size_t)128 * 512 * 4;
  float* muv  = (float*)(ws + o); o += 2048;
  float* varv = (float*)(ws + o); o += 2048;

  const int B = 8;
  const int S = 2048;
  const int CHROWS = 2048;
  tokpe_kernel<<<B * S * DMODEL / 256, 256, 0, stream>>>(x_enc, tok_w, buf0, S);

  int L = S;
  const int Uarr[3] = {24, 21, 21};  // 3*ceil(ln(L)) for 2048,1024,512
  for (int l = 0; l < 3; l++) {
    int U = Uarr[l];
    int u = Uarr[l];
    int BL = B * L;
    idx_kernel<<<(L * U + 255) / 256, 256, 0, stream>>>(idxb, L * U, l, L - 1);
    packqkv_kernel<<<1536 * 512 / 256, 256, 0, stream>>>(
        Wq + (size_t)l * 262144, Wk + (size_t)l * 262144, Wv + (size_t)l * 262144,
        bq + l * 512, bk + l * 512, bv + l * 512, wqkv, bqkv);

    // ---- attention, per batch ----
    dim3 gqkv(1536 / 64, L / 64);
    dim3 gwo(512 / 64, L / 64);
    for (int b = 0; b < B; b++) {
      const float* xb = buf0 + (size_t)b * L * DMODEL;
      gemm64<0, 0, 0><<<gqkv, 256, 0, stream>>>(xb, wqkv, bqkv, nullptr, qkvb,
                                                1536, 512, 0);
      mscore_kernel<<<8 * L / 256, 256, 0, stream>>>(qkvb, idxb, Mb, L, U);
      topk_kernel<<<8, 256, 0, stream>>>(Mb, topb, L, u);
      meanv_kernel<<<8, 256, 0, stream>>>(qkvb, mv, L);
      ctxfill_kernel<<<L * DMODEL / 256, 256, 0, stream>>>(mv, ctxb);
      attnrow_kernel<<<8 * u, 256, 0, stream>>>(qkvb, topb, ctxb, L, u);
      gemm64<0, 1, 0><<<gwo, 256, 0, stream>>>(
          ctxb, Wo + (size_t)l * 262144, bo + l * 512, xb,
          buf1 + (size_t)b * L * DMODEL, 512, 512, 0);
    }
    ln_kernel<<<BL, 256, 0, stream>>>(buf1, g1 + l * DMODEL, be1 + l * DMODEL, buf0);
    // FFN chunks
    for (int r0 = 0; r0 < BL; r0 += CHROWS) {
      dim3 g1d(2048 / 64, CHROWS / 64);
      gemm64<1, 0, 0><<<g1d, 256, 0, stream>>>(
          buf0 + (size_t)r0 * DMODEL, w1 + (size_t)l * 2048 * 512, b1 + l * 2048,
          nullptr, CH, 2048, 512, 0);
      dim3 g2d(512 / 64, CHROWS / 64);
      gemm64<0, 1, 0><<<g2d, 256, 0, stream>>>(
          CH, w2 + (size_t)l * 512 * 2048, b2 + l * 512,
          buf0 + (size_t)r0 * DMODEL, buf1 + (size_t)r0 * DMODEL, 512, 2048, 0);
    }
    ln_kernel<<<BL, 256, 0, stream>>>(buf1, g2 + l * DMODEL, be2 + l * DMODEL, buf0);

    if (l < 2) {
      packw_kernel<<<512 * 1536 / 256, 256, 0, stream>>>(
          dw + (size_t)l * DMODEL * DMODEL * 3, wpack);
      // circular conv as GEMM with on-the-fly im2col (one launch, all rows)
      dim3 gc(512 / 64, BL / 64);
      gemm64<0, 0, 1><<<gc, 256, 0, stream>>>(buf0, wpack, db + l * 512, nullptr,
                                              buf1, 512, 1536, L - 1);
      int nb = BL / 128;
      bnpart_kernel<<<nb, 256, 0, stream>>>(buf1, psum, psq, 128);
      bnfin_kernel<<<2, 256, 0, stream>>>(psum, psq, muv, varv, nb, BL);
      bnpool_kernel<<<(BL / 2) * DMODEL / 256, 256, 0, stream>>>(
          buf1, muv, varv, bng + l * DMODEL, bnb + l * DMODEL, buf0, L);
      L >>= 1;
    }
  }
  int BL = B * L;  // 8*512
  ln_kernel<<<BL, 256, 0, stream>>>(buf0, lnfg, lnfb, buf1);
  end_kernel<<<BL, 64, 0, stream>>>(buf1, endw, endb, out);
}